// Round 5
// baseline (234.089 us; speedup 1.0000x reference)
//
#include <hip/hip_runtime.h>

#define N_GENOMES 4000
#define N_SAMPLES 2048
#define N_GENES   28000
#define N_SEQS    16000
#define MAXW      16     // max genes per seq; P(exceed) ~1e-7 for Poisson(1.75) x 16000
#define ROW4      (N_SAMPLES / 4)   // 512 float4 per row

// ---------------- ELL build: seq -> up to MAXW (genome, pos) pairs ----------------

__global__ void ell_scatter_k(const int* __restrict__ seq_idx,
                              const int* __restrict__ genome_idx,
                              const float* __restrict__ pos,
                              int* __restrict__ counts,
                              int2* __restrict__ ell2) {
    int g = blockIdx.x * blockDim.x + threadIdx.x;
    if (g < N_GENES) {
        int q = seq_idx[g];
        int slot = atomicAdd(&counts[q], 1);
        if (slot < MAXW)
            ell2[q * MAXW + slot] = make_int2(genome_idx[g], __float_as_int(pos[g]));
    }
}

// ---------------- main: ONE WAVE PER SEQ ROW, gene-pair gather batches -----------
// out[q, s] = bias[q] * sum_{g : seq_idx[g]==q} A[gi,s] * 2^(1 - pos[g]*B[gi,s])
//
// Wave w of block b owns q = b*4 + w; lane l owns samples {l*4 + k*256, k=0..7}.
// Every load/store instruction is a dense 64-lane x 16B = 1KB transaction.
// Per gene a wave has 16 dwordx4 (16KB) outstanding; genes processed in pairs
// (32KB in flight). No __syncthreads, no atomics, no LDS: each wave is an
// independent latency chain (rounds 3-4 lesson: per-q serialization, not
// occupancy, was the limiter; avg in-flight bytes/CU must satisfy Little's law).
// __launch_bounds__(256,2): 256-VGPR cap, ample for the ~190-reg live set —
// NO spills (rounds 1-2 lesson: check VGPR_Count/WRITE_SIZE before anything).

__global__ __launch_bounds__(256, 2) void main_wave_k(
    const float* __restrict__ A, const float* __restrict__ B,
    const float* __restrict__ bias,
    const int* __restrict__ counts, const int2* __restrict__ ell2,
    float* __restrict__ out)
{
    const int lane = threadIdx.x & 63;
    const int q    = blockIdx.x * 4 + (threadIdx.x >> 6);   // grid=4000 -> q<16000

    int cnt = counts[q];
    if (cnt > MAXW) cnt = MAXW;
    const int2* __restrict__ row = ell2 + q * MAXW;

    // Unconditional metadata preload (uniform address -> broadcast; slots >= cnt
    // hold poison but are never consumed as addresses).
    const int2 m0 = row[0], m1 = row[1], m2 = row[2], m3 = row[3];

    float4 acc[8];
#pragma unroll
    for (int k = 0; k < 8; ++k) acc[k] = make_float4(0.f, 0.f, 0.f, 0.f);

    const float4* __restrict__ A4 = (const float4*)A;
    const float4* __restrict__ B4 = (const float4*)B;

    // Process a pair of genes: issue all 32 dwordx4 before any consumption.
    auto do_pair = [&](int2 mA, int2 mB, bool second) {
        const float4* Ar0 = A4 + (size_t)mA.x * ROW4 + lane;
        const float4* Br0 = B4 + (size_t)mA.x * ROW4 + lane;
        float4 a0[8], b0[8];
#pragma unroll
        for (int k = 0; k < 8; ++k) { a0[k] = Ar0[k * 64]; b0[k] = Br0[k * 64]; }
        float4 a1[8], b1[8];
        if (second) {
            const float4* Ar1 = A4 + (size_t)mB.x * ROW4 + lane;
            const float4* Br1 = B4 + (size_t)mB.x * ROW4 + lane;
#pragma unroll
            for (int k = 0; k < 8; ++k) { a1[k] = Ar1[k * 64]; b1[k] = Br1[k * 64]; }
        }
        const float pA = __int_as_float(mA.y);
#pragma unroll
        for (int k = 0; k < 8; ++k) {
            acc[k].x += a0[k].x * exp2f(1.0f - pA * b0[k].x);
            acc[k].y += a0[k].y * exp2f(1.0f - pA * b0[k].y);
            acc[k].z += a0[k].z * exp2f(1.0f - pA * b0[k].z);
            acc[k].w += a0[k].w * exp2f(1.0f - pA * b0[k].w);
        }
        if (second) {
            const float pB = __int_as_float(mB.y);
#pragma unroll
            for (int k = 0; k < 8; ++k) {
                acc[k].x += a1[k].x * exp2f(1.0f - pB * b1[k].x);
                acc[k].y += a1[k].y * exp2f(1.0f - pB * b1[k].y);
                acc[k].z += a1[k].z * exp2f(1.0f - pB * b1[k].z);
                acc[k].w += a1[k].w * exp2f(1.0f - pB * b1[k].w);
            }
        }
    };

    if (cnt > 0) do_pair(m0, m1, cnt > 1);
    if (cnt > 2) do_pair(m2, m3, cnt > 3);
#pragma unroll 1
    for (int g = 4; g < cnt; g += 2)            // rare tail (~3.4% of q's)
        do_pair(row[g], row[g + 1], g + 1 < cnt);  // g+1 <= 15: always in-bounds

    const float bq = bias[q];
    float4* __restrict__ Or = (float4*)out + (size_t)q * ROW4 + lane;
#pragma unroll
    for (int k = 0; k < 8; ++k) {
        float4 o;
        o.x = acc[k].x * bq; o.y = acc[k].y * bq;
        o.z = acc[k].z * bq; o.w = acc[k].w * bq;
        Or[k * 64] = o;
    }
}

// ---------------- launch ----------------

extern "C" void kernel_launch(void* const* d_in, const int* in_sizes, int n_in,
                              void* d_out, int out_size, void* d_ws, size_t ws_size,
                              hipStream_t stream) {
    const float* A          = (const float*)d_in[0];   // (4000, 2048)
    const float* B          = (const float*)d_in[1];   // (4000, 2048)
    const float* bias       = (const float*)d_in[2];   // (16000,)
    const float* pos        = (const float*)d_in[3];   // (28000,)
    const int*   genome_idx = (const int*)d_in[4];     // (28000,)
    const int*   seq_idx    = (const int*)d_in[5];     // (28000,)
    float*       out        = (float*)d_out;           // (16000, 2048)

    // ws layout: [counts: 16000 int][ell2: 16000*16 int2]
    int*  counts = (int*)d_ws;
    int2* ell2   = (int2*)((char*)d_ws + ((N_SEQS * sizeof(int) + 15) & ~15));

    hipMemsetAsync(counts, 0, N_SEQS * sizeof(int), stream);
    ell_scatter_k<<<(N_GENES + 255) / 256, 256, 0, stream>>>(seq_idx, genome_idx, pos,
                                                             counts, ell2);
    main_wave_k<<<N_SEQS / 4, 256, 0, stream>>>(A, B, bias, counts, ell2, out);
}